// Round 11
// baseline (218.767 us; speedup 1.0000x reference)
//
#include <hip/hip_runtime.h>
#include <hip/hip_bf16.h>
#include <math.h>

#define HW 4096
#define NC 512
#define NB 4

typedef float f32x4 __attribute__((ext_vector_type(4)));
typedef float f32x16 __attribute__((ext_vector_type(16)));
typedef short bf16x8 __attribute__((ext_vector_type(8)));
typedef unsigned int u32;
typedef u32 u32x4 __attribute__((ext_vector_type(4)));
typedef unsigned short ushort_t;

#define GLOAD_LDS(g, s) __builtin_amdgcn_global_load_lds((const __attribute__((address_space(1))) void*)(g), (__attribute__((address_space(3))) void*)(s), 16, 0, 0)

__device__ __forceinline__ unsigned short f2bf(float f){
  unsigned int u = __builtin_bit_cast(unsigned int, f);
  u += 0x7FFFu + ((u >> 16) & 1u);
  return (unsigned short)(u >> 16);
}
__device__ __forceinline__ float bf2f(unsigned short h){
  unsigned int u = ((unsigned int)h) << 16;
  return __builtin_bit_cast(float, u);
}

// ---------------- W -> bf16 hi (+lo for q/k rows 0..127) ----------------
__global__ __launch_bounds__(256) void wsplit_kernel(
    const float* __restrict__ Wq, const float* __restrict__ Wk,
    const float* __restrict__ Wv, ushort_t* __restrict__ wh, ushort_t* __restrict__ wl)
{
  long e = ((long)blockIdx.x * 256 + threadIdx.x) * 8;
  int r = (int)(e >> 9), c = (int)(e & 511);
  const float* src = (r < 64)  ? Wq + (long)r * 512 + c
                   : (r < 128) ? Wk + (long)(r - 64) * 512 + c
                               : Wv + (long)(r - 128) * 512 + c;
  f32x4 v0 = *reinterpret_cast<const f32x4*>(src);
  f32x4 v1 = *reinterpret_cast<const f32x4*>(src + 4);
  ushort_t h[8], l[8];
  #pragma unroll
  for (int j = 0; j < 4; j++){ h[j] = f2bf(v0[j]); l[j] = f2bf(v0[j] - bf2f(h[j])); }
  #pragma unroll
  for (int j = 0; j < 4; j++){ h[4+j] = f2bf(v1[j]); l[4+j] = f2bf(v1[j] - bf2f(h[4+j])); }
  *reinterpret_cast<bf16x8*>(wh + e) = *reinterpret_cast<bf16x8*>(h);
  if (r < 128) *reinterpret_cast<bf16x8*>(wl + e) = *reinterpret_cast<bf16x8*>(l);
}

// ---------------- x [b][c][px] fp32 -> xt hi/lo [b][px][c] bf16 ----------------
__global__ __launch_bounds__(256) void split_kernel(
    const float* __restrict__ x, ushort_t* __restrict__ xth, ushort_t* __restrict__ xtl)
{
  const int i0 = blockIdx.x * 64;
  const int c0 = blockIdx.y * 64;
  const int b  = blockIdx.z;
  const int tid = threadIdx.x;
  const int tx = tid & 63, ty = tid >> 6;
  __shared__ float ts[64][65];
  #pragma unroll
  for (int u = 0; u < 16; u++){
    int cl = ty * 16 + u;
    ts[cl][tx] = x[((long)b * NC + c0 + cl) * HW + i0 + tx];
  }
  __syncthreads();
  const int px = tid >> 2;
  const int cs = (tid & 3) * 16;
  ushort_t h[16], l[16];
  #pragma unroll
  for (int e = 0; e < 16; e++){
    float v = ts[cs + e][px];
    h[e] = f2bf(v);
    l[e] = f2bf(v - bf2f(h[e]));
  }
  long base = ((long)b * HW + i0 + px) * 512 + c0 + cs;
  *reinterpret_cast<bf16x8*>(xth + base)     = *reinterpret_cast<bf16x8*>(h);
  *reinterpret_cast<bf16x8*>(xth + base + 8) = *reinterpret_cast<bf16x8*>(h + 8);
  *reinterpret_cast<bf16x8*>(xtl + base)     = *reinterpret_cast<bf16x8*>(l);
  *reinterpret_cast<bf16x8*>(xtl + base + 8) = *reinterpret_cast<bf16x8*>(l + 8);
}

// ---------------- MFMA projection GEMM (unchanged; q pre-scaled by log2 e) ----------------
__global__ __launch_bounds__(256) void gemm_kernel(
    const ushort_t* __restrict__ xth, const ushort_t* __restrict__ xtl,
    const ushort_t* __restrict__ wh, const ushort_t* __restrict__ wl,
    const float* __restrict__ bq, const float* __restrict__ bk, const float* __restrict__ bv,
    ushort_t* __restrict__ qhi, ushort_t* __restrict__ qlo,
    ushort_t* __restrict__ khi, ushort_t* __restrict__ klo,
    ushort_t* __restrict__ vv)
{
  extern __shared__ char lds[];
  const int it = blockIdx.x;
  const int rg = blockIdx.y;
  const int b  = blockIdx.z;
  const int i0 = it * 128;
  const int tid = threadIdx.x;
  const int w = tid >> 6;
  const int lane = tid & 63;
  const int g = lane >> 4, n = lane & 15;
  const int wy = w >> 1, wx = w & 1;

  f32x4 acc[4][4];
  #pragma unroll
  for (int a = 0; a < 4; a++)
    #pragma unroll
    for (int m = 0; m < 4; m++) acc[a][m] = (f32x4){0.f, 0.f, 0.f, 0.f};

  const long xrow = (long)b * HW + i0;

  auto stage = [&](int bsel, int c0s){
    char* dbase = lds + bsel * 32768 + (w << 10);
    #pragma unroll
    for (int u = 0; u < 4; u++){
      int idx = (u << 8) | tid;
      int px = idx >> 3;
      int chs = (idx & 7) ^ (px & 7);
      long go = (xrow + px) * 512 + c0s + chs * 8;
      GLOAD_LDS(xth + go, dbase + (u << 12));
      GLOAD_LDS(xtl + go, dbase + 16384 + (u << 12));
    }
  };

  stage(0, 0);
  asm volatile("s_waitcnt vmcnt(0)" ::: "memory");
  __syncthreads();

  int cur = 0;
  for (int t = 0; t < 8; t++){
    const int c0 = t << 6;
    bf16x8 wfh[4][2], wfl[4][2];
    #pragma unroll
    for (int a = 0; a < 4; a++){
      long R = (long)(rg * 128 + wx * 64 + a * 16 + n) * 512 + c0 + g * 8;
      wfh[a][0] = *reinterpret_cast<const bf16x8*>(wh + R);
      wfh[a][1] = *reinterpret_cast<const bf16x8*>(wh + R + 32);
    }
    if (rg == 0){
      #pragma unroll
      for (int a = 0; a < 4; a++){
        long R = (long)(wx * 64 + a * 16 + n) * 512 + c0 + g * 8;
        wfl[a][0] = *reinterpret_cast<const bf16x8*>(wl + R);
        wfl[a][1] = *reinterpret_cast<const bf16x8*>(wl + R + 32);
      }
    }
    if (t < 7) stage(cur ^ 1, (t + 1) << 6);
    bf16x8 xh[4][2], xl[4][2];
    const char* buf = lds + cur * 32768;
    #pragma unroll
    for (int m = 0; m < 4; m++){
      int px = wy * 64 + m * 16 + n;
      const char* row = buf + px * 128;
      #pragma unroll
      for (int ks = 0; ks < 2; ks++){
        int off = (((ks << 2) | g) ^ (px & 7)) << 4;
        xh[m][ks] = *reinterpret_cast<const bf16x8*>(row + off);
        xl[m][ks] = *reinterpret_cast<const bf16x8*>(row + 16384 + off);
      }
    }
    __builtin_amdgcn_s_setprio(1);
    if (rg == 0){
      #pragma unroll
      for (int a = 0; a < 4; a++)
        #pragma unroll
        for (int m = 0; m < 4; m++)
          #pragma unroll
          for (int ks = 0; ks < 2; ks++){
            acc[a][m] = __builtin_amdgcn_mfma_f32_16x16x32_bf16(xh[m][ks], wfh[a][ks], acc[a][m], 0, 0, 0);
            acc[a][m] = __builtin_amdgcn_mfma_f32_16x16x32_bf16(xl[m][ks], wfh[a][ks], acc[a][m], 0, 0, 0);
            acc[a][m] = __builtin_amdgcn_mfma_f32_16x16x32_bf16(xh[m][ks], wfl[a][ks], acc[a][m], 0, 0, 0);
          }
    } else {
      #pragma unroll
      for (int a = 0; a < 4; a++)
        #pragma unroll
        for (int m = 0; m < 4; m++)
          #pragma unroll
          for (int ks = 0; ks < 2; ks++){
            acc[a][m] = __builtin_amdgcn_mfma_f32_16x16x32_bf16(wfh[a][ks], xh[m][ks], acc[a][m], 0, 0, 0);
            acc[a][m] = __builtin_amdgcn_mfma_f32_16x16x32_bf16(wfh[a][ks], xl[m][ks], acc[a][m], 0, 0, 0);
          }
    }
    __builtin_amdgcn_s_setprio(0);
    asm volatile("s_waitcnt vmcnt(0)" ::: "memory");
    __syncthreads();
    cur ^= 1;
  }

  if (rg == 0){
    ushort_t* hs = wx ? khi : qhi;
    ushort_t* ls = wx ? klo : qlo;
    const float* bias = wx ? bk : bq;
    const float qscale = wx ? 1.0f : 1.44269504088896f;
    #pragma unroll
    for (int a = 0; a < 4; a++){
      float bb = bias[a * 16 + n];
      #pragma unroll
      for (int m = 0; m < 4; m++){
        #pragma unroll
        for (int r4 = 0; r4 < 4; r4++){
          int px = wy * 64 + m * 16 + g * 4 + r4;
          float v = (acc[a][m][r4] + bb) * qscale;
          ushort_t h = f2bf(v);
          ushort_t l = f2bf(v - bf2f(h));
          long ad = (xrow + px) * 64 + a * 16 + n;
          hs[ad] = h;
          ls[ad] = l;
        }
      }
    }
  } else {
    #pragma unroll
    for (int a = 0; a < 4; a++){
      #pragma unroll
      for (int r4 = 0; r4 < 4; r4++){
        int C = (rg - 1) * 128 + wx * 64 + a * 16 + g * 4 + r4;
        float bb = bv[C];
        #pragma unroll
        for (int m = 0; m < 4; m++){
          int px = wy * 64 + m * 16 + n;
          vv[((long)b * NC + C) * HW + i0 + px] = f2bf(acc[a][m][r4] + bb);
        }
      }
    }
  }
}

// ---------------- flash attention: single-barrier counted-vmcnt pipeline ----------------
// 1D grid 256; decode: xcd = wgid&7 -> (jh, b), qt = wgid>>3.
// 8 waves: rg = w>>1 (32 q rows), ch = w&1 (256-c half). 64 iters x 32-j tiles.
// Per iter: stage K[t+2],V[t+2] -> PV(t) (pa in regs) -> QK(t+1)+SM -> pa regs
//           -> vmcnt(4) + raw s_barrier (V[t+2] stays in flight).
// LDS 104K: V triple buf [3][256 rows c-pair][128B] chunk pos jc^(R&3);
//           K dbuf [2][32 j][128B] XOR-8 (at offset 96K).
__global__ __launch_bounds__(512, 1) void attn_kernel(
    const ushort_t* __restrict__ qhi, const ushort_t* __restrict__ qlo,
    const ushort_t* __restrict__ khi,
    const ushort_t* __restrict__ vv,
    ushort_t* __restrict__ p0, ushort_t* __restrict__ p1,
    float* __restrict__ mbuf, float* __restrict__ lbuf)
{
  extern __shared__ char smem[];
  const int KB = 98304;
  const int wgid = blockIdx.x;
  const int xcd = wgid & 7;
  const int jh = xcd >> 2;
  const int b  = xcd & 3;
  const int qt = wgid >> 3;
  const int tid = threadIdx.x;
  const int w = tid >> 6;
  const int lane = tid & 63;
  const int q32 = lane & 31;
  const int hh = lane >> 5;
  const int rg = w >> 1, ch = w & 1;
  const int i0w = qt * 128 + rg * 32;
  const int c0w = ch * 256;
  const int jbase = jh * 2048;

  // Q fragments (B-operand): col q = lane&31, k(d) = chain*16 + hh*8 + e
  bf16x8 aqh[4], aql[4];
  #pragma unroll
  for (int c = 0; c < 4; c++){
    long qb = ((long)b * HW + i0w + q32) * 64 + c * 16 + hh * 8;
    aqh[c] = *reinterpret_cast<const bf16x8*>(qhi + qb);
    aql[c] = *reinterpret_cast<const bf16x8*>(qlo + qb);
  }

  f32x16 acc[8];
  #pragma unroll
  for (int ct = 0; ct < 8; ct++)
    #pragma unroll
    for (int r = 0; r < 16; r++) acc[ct][r] = 0.f;
  float mrow = -1e30f, lrow = 0.f;
  bf16x8 pa[2];

  // V staging chunk math: ci -> R=ci>>3, half=(ci>>2)&1, pos=ci&3, jc=pos^(R&3), c=2R+half
  auto stageV = [&](int vbsel, int j0){
    char* vd = smem + vbsel * 32768;
    #pragma unroll
    for (int u = 0; u < 4; u++){
      int ci = (w << 8) | (u << 6) | lane;
      int R = ci >> 3, half = (ci >> 2) & 1, pos = ci & 3;
      int jc = pos ^ (R & 3);
      int c = 2 * R + half;
      GLOAD_LDS(vv + ((long)b * NC + c) * HW + j0 + jc * 8, vd + ci * 16);
    }
  };
  // K staging: ci -> kj=ci>>3, pos=ci&7, dblk=pos^(kj&7); one EXEC-masked instr/wave
  auto stageK = [&](int kbsel, int j0){
    if (lane < 32){
      int ci = (w << 5) | lane;
      int kj = ci >> 3, pos = ci & 7;
      int db = pos ^ (kj & 7);
      GLOAD_LDS(khi + ((long)b * HW + j0 + kj) * 64 + db * 8,
                smem + KB + (kbsel << 12) + ci * 16);
    }
  };

  // QK(tt) from Kbuf[tt&1] + softmax + pack -> pa (in registers)
  auto qk_sm = [&](int tt){
    const char* krow = smem + KB + ((tt & 1) << 12) + q32 * 128;
    const int r7 = q32 & 7;
    f32x16 s1, s2;
    #pragma unroll
    for (int r = 0; r < 16; r++){ s1[r] = 0.f; s2[r] = 0.f; }
    __builtin_amdgcn_s_setprio(1);
    #pragma unroll
    for (int c = 0; c < 4; c++){
      int off = (((c << 1) | hh) ^ r7) << 4;
      bf16x8 kh = *(const bf16x8*)(krow + off);
      s1 = __builtin_amdgcn_mfma_f32_32x32x16_bf16(kh, aqh[c], s1, 0, 0, 0);
      s2 = __builtin_amdgcn_mfma_f32_32x32x16_bf16(kh, aql[c], s2, 0, 0, 0);
    }
    __builtin_amdgcn_s_setprio(0);
    f32x16 sv;
    #pragma unroll
    for (int r = 0; r < 16; r++) sv[r] = s1[r] + s2[r];
    // defer-max (log2 units)
    float m8[8];
    #pragma unroll
    for (int r = 0; r < 8; r++) m8[r] = fmaxf(sv[r], sv[r + 8]);
    float m4a = fmaxf(m8[0], m8[4]), m4b = fmaxf(m8[1], m8[5]);
    float m4c = fmaxf(m8[2], m8[6]), m4d = fmaxf(m8[3], m8[7]);
    float tmx = fmaxf(fmaxf(m4a, m4b), fmaxf(m4c, m4d));
    tmx = fmaxf(tmx, __shfl_xor(tmx, 32));
    if (__any(tmx > mrow + 11.5f)){
      float mnew = fmaxf(mrow, tmx);
      float sc = exp2f(mrow - mnew);
      lrow *= sc;
      #pragma unroll
      for (int ct = 0; ct < 8; ct++)
        #pragma unroll
        for (int r = 0; r < 16; r++) acc[ct][r] *= sc;
      mrow = mnew;
    }
    #pragma unroll
    for (int r = 0; r < 16; r++) sv[r] = exp2f(sv[r] - mrow);
    float rs = 0.f;
    #pragma unroll
    for (int r = 0; r < 16; r++) rs += sv[r];
    rs += __shfl_xor(rs, 32);
    lrow += rs;
    u32 pk[8];
    #pragma unroll
    for (int i = 0; i < 8; i++){
      float a = sv[2 * i], bb = sv[2 * i + 1];
      u32 d;
      asm("v_cvt_pk_bf16_f32 %0, %1, %2" : "=v"(d) : "v"(a), "v"(bb));
      pk[i] = d;
    }
    #pragma unroll
    for (int cc = 0; cc < 2; cc++){
      u32 a0 = pk[4 * cc + 0], b0 = pk[4 * cc + 2];
      u32 a1 = pk[4 * cc + 1], b1 = pk[4 * cc + 3];
      asm volatile("v_permlane32_swap_b32 %0, %1" : "+v"(a0), "+v"(b0));
      asm volatile("v_permlane32_swap_b32 %0, %1" : "+v"(a1), "+v"(b1));
      u32x4 wv;
      wv[0] = a0; wv[1] = a1; wv[2] = b0; wv[3] = b1;
      pa[cc] = __builtin_bit_cast(bf16x8, wv);
    }
  };

  // ---- prologue: K[0],K[1],V[0],V[1]
  stageK(0, jbase);
  stageK(1, jbase + 32);
  stageV(0, jbase);
  stageV(1, jbase + 32);
  asm volatile("s_waitcnt vmcnt(0)" ::: "memory");
  __builtin_amdgcn_s_barrier();
  __builtin_amdgcn_sched_barrier(0);

  // ---- priming: QK[0]+SM -> pa regs; barrier before iter0 overwrites Kbuf0
  qk_sm(0);
  __builtin_amdgcn_sched_barrier(0);
  __builtin_amdgcn_s_barrier();
  __builtin_amdgcn_sched_barrier(0);

  for (int t = 0; t < 64; t++){
    // 1. stage K[t+2] -> Kbuf[t&1], V[t+2] -> Vbuf[(t+2)%3]  (K first: vmcnt order)
    if (t < 62){
      int j2 = jbase + (t + 2) * 32;
      stageK(t & 1, j2);
      stageV((t + 2) % 3, j2);
    }
    // 2. PV(t) from Vbuf[t%3] with pa regs
    {
      const char* vb = smem + (t % 3) * 32768;
      __builtin_amdgcn_s_setprio(1);
      #pragma unroll
      for (int ct = 0; ct < 8; ct++){
        int c = c0w + ct * 32 + q32;
        int R = c >> 1;
        const char* vrow = vb + R * 128 + (c & 1) * 64;
        int r3 = R & 3;
        #pragma unroll
        for (int ks = 0; ks < 2; ks++){
          int pos = ((ks << 1) | hh) ^ r3;
          bf16x8 vf = *(const bf16x8*)(vrow + pos * 16);
          acc[ct] = __builtin_amdgcn_mfma_f32_32x32x16_bf16(vf, pa[ks], acc[ct], 0, 0, 0);
        }
      }
      __builtin_amdgcn_s_setprio(0);
    }
    // 3. QK(t+1)+SM -> pa for next iter
    if (t < 63) qk_sm(t + 1);
    // 4. counted-vmcnt raw barrier (V[t+2] stays in flight)
    if (t < 62){
      __builtin_amdgcn_sched_barrier(0);
      asm volatile("s_waitcnt vmcnt(4)" ::: "memory");
      __builtin_amdgcn_s_barrier();
      __builtin_amdgcn_sched_barrier(0);
    } else if (t == 62){
      __builtin_amdgcn_sched_barrier(0);
      asm volatile("s_waitcnt vmcnt(0)" ::: "memory");
      __builtin_amdgcn_s_barrier();
      __builtin_amdgcn_sched_barrier(0);
    }
  }

  // epilogue: unnormalized partial bf16, [b][c][i] layout (coalesced in i)
  ushort_t* pd = jh ? p1 : p0;
  const int i = i0w + q32;
  #pragma unroll
  for (int ct = 0; ct < 8; ct++){
    #pragma unroll
    for (int r = 0; r < 16; r++){
      int c = c0w + ct * 32 + (r & 3) + 8 * (r >> 2) + 4 * hh;
      pd[((long)b * NC + c) * HW + i] = f2bf(acc[ct][r]);
    }
  }
  if (ch == 0 && lane < 32){
    int gi = b * HW + i0w + lane;
    mbuf[jh * (NB * HW) + gi] = mrow;
    lbuf[jh * (NB * HW) + gi] = lrow;
  }
}

// ---------------- combine halves + epilogue: out = gamma * O + x ----------------
__global__ __launch_bounds__(256) void comb_kernel(
    const ushort_t* __restrict__ p0, const ushort_t* __restrict__ p1,
    const float* __restrict__ mbuf, const float* __restrict__ lbuf,
    const float* __restrict__ x, const float* __restrict__ gamma,
    float* __restrict__ out)
{
  const int it = blockIdx.x;
  const int ct = blockIdx.y;
  const int b  = blockIdx.z;
  const int i0 = it * 64, c0 = ct * 64;
  const int tid = threadIdx.x;
  const int tx = tid & 63, ty = tid >> 6;
  __shared__ float f0s[64], f1s[64];
  const float gm = gamma[0];
  if (tid < 64){
    int gi = b * HW + i0 + tid;
    float m0 = mbuf[gi], m1 = mbuf[NB * HW + gi];
    float l0 = lbuf[gi], l1 = lbuf[NB * HW + gi];
    float M = fmaxf(m0, m1);
    float w0 = exp2f(m0 - M), w1 = exp2f(m1 - M);
    float rden = 1.f / (w0 * l0 + w1 * l1);
    f0s[tid] = w0 * rden;
    f1s[tid] = w1 * rden;
  }
  __syncthreads();
  #pragma unroll
  for (int u = 0; u < 16; u++){
    int cl = ty * 16 + u;
    long idx = ((long)b * NC + c0 + cl) * HW + i0 + tx;
    float o = f0s[tx] * bf2f(p0[idx]) + f1s[tx] * bf2f(p1[idx]);
    out[idx] = fmaf(gm, o, x[idx]);
  }
}

extern "C" void kernel_launch(void* const* d_in, const int* in_sizes, int n_in,
                              void* d_out, int out_size, void* d_ws, size_t ws_size,
                              hipStream_t stream)
{
  const float* x  = (const float*)d_in[0];
  const float* Wq = (const float*)d_in[1];
  const float* bq = (const float*)d_in[2];
  const float* Wk = (const float*)d_in[3];
  const float* bk = (const float*)d_in[4];
  const float* Wv = (const float*)d_in[5];
  const float* bv = (const float*)d_in[6];
  const float* gamma = (const float*)d_in[7];
  float* out = (float*)d_out;

  char* ws = (char*)d_ws;
  const size_t MB = 1024 * 1024;
  ushort_t* xth = (ushort_t*)(ws);                 // 16 MB, reused as partial0
  ushort_t* xtl = (ushort_t*)(ws + 16 * MB);       // 16 MB, reused as partial1
  ushort_t* wh  = (ushort_t*)(ws + 32 * MB);       // 640 KB
  ushort_t* wl  = (ushort_t*)(ws + 32 * MB + 655360);  // 128 KB
  ushort_t* qhi = (ushort_t*)(ws + 33 * MB);       // 2 MB each
  ushort_t* qlo = (ushort_t*)(ws + 35 * MB);
  ushort_t* khi = (ushort_t*)(ws + 37 * MB);
  ushort_t* klo = (ushort_t*)(ws + 39 * MB);       // written by gemm, unused by attn
  ushort_t* vv  = (ushort_t*)(ws + 41 * MB);       // 16 MB
  float*    mbuf = (float*)(ws + 57 * MB);         // 128 KB
  float*    lbuf = (float*)(ws + 57 * MB + 131072);// 128 KB
  ushort_t* part0 = xth;
  ushort_t* part1 = xtl;

  wsplit_kernel<<<dim3(160), dim3(256), 0, stream>>>(Wq, Wk, Wv, wh, wl);
  split_kernel<<<dim3(64, 8, NB), dim3(256), 0, stream>>>(x, xth, xtl);

  const int GSMEM = 65536;
  hipFuncSetAttribute((const void*)gemm_kernel,
                      hipFuncAttributeMaxDynamicSharedMemorySize, GSMEM);
  gemm_kernel<<<dim3(32, 5, NB), dim3(256), GSMEM, stream>>>(
      xth, xtl, wh, wl, bq, bk, bv, qhi, qlo, khi, klo, vv);

  const int ASMEM = 106496;  // 96K V triple-buf + 8K K dbuf
  hipFuncSetAttribute((const void*)attn_kernel,
                      hipFuncAttributeMaxDynamicSharedMemorySize, ASMEM);
  attn_kernel<<<dim3(256), dim3(512), ASMEM, stream>>>(
      qhi, qlo, khi, vv, part0, part1, mbuf, lbuf);

  comb_kernel<<<dim3(64, 8, NB), dim3(256), 0, stream>>>(
      part0, part1, mbuf, lbuf, x, gamma, out);
}